// Round 5
// baseline (238.305 us; speedup 1.0000x reference)
//
#include <hip/hip_runtime.h>
#include <cmath>

#define TABLE_NUM 16
#define T_SIZE    4096
#define Z_DIM     512
#define IMG       256
#define D_TAB     (TABLE_NUM * T_SIZE * 2)       // 131072
#define BATCH     8
#define HID       64
#define N_PIX     (IMG * IMG)                    // 65536
#define PRIME_Y   2654435761u

typedef _Float16 v8h  __attribute__((ext_vector_type(8)));
typedef _Float16 v2h  __attribute__((ext_vector_type(2)));
typedef float    v4f  __attribute__((ext_vector_type(4)));

struct ResArr { float r[TABLE_NUM]; };

// ---------------------------------------------------------------------------
// MEASUREMENT ROUND: source identical to R4 except gen_tables is launched 3x
// (idempotent). gen_dur = (T_R5 - T_R4) / 2 isolates the kernel split that
// rocprof's top-5 cutoff hides.
// ---------------------------------------------------------------------------

__global__ void prep_weights(const float* __restrict__ w1, const float* __restrict__ w2,
                             const float* __restrict__ w3,
                             _Float16* __restrict__ w1T, _Float16* __restrict__ w2T,
                             _Float16* __restrict__ w3T)
{
    const int t = threadIdx.x;
    for (int i = t; i < HID * 32; i += 256) {          // w1T[64][32] <- w1[32][64]
        int n = i >> 5, k = i & 31;
        w1T[i] = (_Float16)w1[k * HID + n];
    }
    for (int i = t; i < HID * HID; i += 256) {         // w2T[64][64] <- w2[64][64]
        int n = i >> 6, k = i & 63;
        w2T[i] = (_Float16)w2[k * HID + n];
    }
    for (int i = t; i < 16 * HID; i += 256) {          // w3T[16][64] <- w3[64][3], pad
        int n = i >> 6, k = i & 63;
        w3T[i] = (_Float16)(n < 3 ? w3[k * 3 + n] : 0.f);
    }
}

__global__ __launch_bounds__(256) void gen_tables(
    const float* __restrict__ z, const float* __restrict__ w,
    const float* __restrict__ bt, float* __restrict__ tabs)
{
    const int n = blockIdx.x * 256 + threadIdx.x;      // column 0..131071
    float acc[BATCH];
#pragma unroll
    for (int b = 0; b < BATCH; ++b) acc[b] = 0.f;

#pragma unroll 16
    for (int k = 0; k < Z_DIM; ++k) {
        float wv = w[(size_t)k * D_TAB + n];
#pragma unroll
        for (int b = 0; b < BATCH; ++b)
            acc[b] = fmaf(z[b * Z_DIM + k], wv, acc[b]);
    }

    float bv = bt[n];
#pragma unroll
    for (int b = 0; b < BATCH; ++b)
        tabs[(size_t)b * D_TAB + n] = acc[b] + bv;
}

__global__ __launch_bounds__(256) void hash_mlp(
    const float* __restrict__ tabs,
    const _Float16* __restrict__ w1T, const _Float16* __restrict__ w2T,
    const _Float16* __restrict__ w3T,
    const float* __restrict__ b1, const float* __restrict__ b2,
    const float* __restrict__ b3,
    float* __restrict__ out, ResArr res)
{
    __shared__ _Float16 mbuf[4][64][72];
    const int tid  = threadIdx.x;
    const int wid  = tid >> 6;
    const int lane = tid & 63;
    const int b    = blockIdx.x & 7;          // batch == XCD (round-robin)
    const int tile = blockIdx.x >> 3;         // 0..255 -> 16x16 block of pixels
    const int ti   = tile >> 4;
    const int tj   = tile & 15;
    const int i0   = ti * 16 + wid * 4;       // this wave's 4 i-rows
    const int j0   = tj * 16;                 // 16 j-cols

    const int di = lane >> 4, dj = lane & 15;
    const float cx = ((float)(i0 + di) + 0.5f) * (1.0f / IMG);
    const float cy = ((float)(j0 + dj) + 0.5f) * (1.0f / IMG);
    const float* tb = tabs + (size_t)b * D_TAB;
    const float2* tb2 = reinterpret_cast<const float2*>(tb);

    // ---- hash-grid features: 16 levels, f16 pairs straight to LDS ----
#pragma unroll 4
    for (int l = 0; l < TABLE_NUM; ++l) {
        float r  = res.r[l];
        float px = cx * r, py = cy * r;
        float fx0 = floorf(px), fy0 = floorf(py);
        float fx = px - fx0, fy = py - fy0;
        unsigned x0 = (unsigned)(int)fx0, y0 = (unsigned)(int)fy0;
        unsigned hy0 = y0 * PRIME_Y, hy1 = (y0 + 1u) * PRIME_Y;
        unsigned i00 = (x0 ^ hy0) & (T_SIZE - 1);
        unsigned i10 = ((x0 + 1u) ^ hy0) & (T_SIZE - 1);
        unsigned i01 = (x0 ^ hy1) & (T_SIZE - 1);
        unsigned i11 = ((x0 + 1u) ^ hy1) & (T_SIZE - 1);
        const float2* tl = tb2 + l * T_SIZE;
        float2 f00 = tl[i00], f10 = tl[i10], f01 = tl[i01], f11 = tl[i11];
        float w00 = (1.f - fx) * (1.f - fy);
        float w10 = fx * (1.f - fy);
        float w01 = (1.f - fx) * fy;
        float w11 = fx * fy;
        float e0 = f00.x * w00 + f10.x * w10 + f01.x * w01 + f11.x * w11;
        float e1 = f00.y * w00 + f10.y * w10 + f01.y * w01 + f11.y * w11;
        v2h p; p.x = (_Float16)e0; p.y = (_Float16)e1;
        *reinterpret_cast<v2h*>(&mbuf[wid][lane][2 * l]) = p;
    }

    const int arow = lane & 15;        // A row / B col / C col
    const int kgrp = lane >> 4;        // k-group

    float bias1v[4], bias2v[4];
#pragma unroll
    for (int nt = 0; nt < 4; ++nt) {
        bias1v[nt] = b1[nt * 16 + arow];
        bias2v[nt] = b2[nt * 16 + arow];
    }
    const float bias3 = (arow < 3) ? b3[arow] : 0.f;

    v8h bf1[4], bf2a[4], bf2b[4];
#pragma unroll
    for (int nt = 0; nt < 4; ++nt) {
        bf1[nt]  = *reinterpret_cast<const v8h*>(&w1T[(nt * 16 + arow) * 32 + kgrp * 8]);
        bf2a[nt] = *reinterpret_cast<const v8h*>(&w2T[(nt * 16 + arow) * 64 + kgrp * 8]);
        bf2b[nt] = *reinterpret_cast<const v8h*>(&w2T[(nt * 16 + arow) * 64 + 32 + kgrp * 8]);
    }
    v8h bf3a = *reinterpret_cast<const v8h*>(&w3T[arow * 64 + kgrp * 8]);
    v8h bf3b = *reinterpret_cast<const v8h*>(&w3T[arow * 64 + 32 + kgrp * 8]);

    // ---- layer 1: 32 -> 64 ----
    v8h a1[4];
#pragma unroll
    for (int mt = 0; mt < 4; ++mt)
        a1[mt] = *reinterpret_cast<const v8h*>(&mbuf[wid][mt * 16 + arow][kgrp * 8]);

    v4f c1[4][4];
#pragma unroll
    for (int nt = 0; nt < 4; ++nt)
#pragma unroll
        for (int mt = 0; mt < 4; ++mt) {
            v4f c = {0.f, 0.f, 0.f, 0.f};
            c = __builtin_amdgcn_mfma_f32_16x16x32_f16(a1[mt], bf1[nt], c, 0, 0, 0);
#pragma unroll
            for (int e = 0; e < 4; ++e)
                c1[mt][nt][e] = fmaxf(c[e] + bias1v[nt], 0.f);
        }

#pragma unroll
    for (int mt = 0; mt < 4; ++mt)
#pragma unroll
        for (int nt = 0; nt < 4; ++nt)
#pragma unroll
            for (int e = 0; e < 4; ++e)
                mbuf[wid][mt * 16 + kgrp * 4 + e][nt * 16 + arow] = (_Float16)c1[mt][nt][e];

    // ---- layer 2: 64 -> 64 ----
    v8h a2[4][2];
#pragma unroll
    for (int mt = 0; mt < 4; ++mt) {
        a2[mt][0] = *reinterpret_cast<const v8h*>(&mbuf[wid][mt * 16 + arow][kgrp * 8]);
        a2[mt][1] = *reinterpret_cast<const v8h*>(&mbuf[wid][mt * 16 + arow][32 + kgrp * 8]);
    }
    v4f c2[4][4];
#pragma unroll
    for (int nt = 0; nt < 4; ++nt)
#pragma unroll
        for (int mt = 0; mt < 4; ++mt) {
            v4f c = {0.f, 0.f, 0.f, 0.f};
            c = __builtin_amdgcn_mfma_f32_16x16x32_f16(a2[mt][0], bf2a[nt], c, 0, 0, 0);
            c = __builtin_amdgcn_mfma_f32_16x16x32_f16(a2[mt][1], bf2b[nt], c, 0, 0, 0);
#pragma unroll
            for (int e = 0; e < 4; ++e)
                c2[mt][nt][e] = fmaxf(c[e] + bias2v[nt], 0.f);
        }

#pragma unroll
    for (int mt = 0; mt < 4; ++mt)
#pragma unroll
        for (int nt = 0; nt < 4; ++nt)
#pragma unroll
            for (int e = 0; e < 4; ++e)
                mbuf[wid][mt * 16 + kgrp * 4 + e][nt * 16 + arow] = (_Float16)c2[mt][nt][e];

    // ---- layer 3: 64 -> 3 (padded 16), tanh, coalesced row stores ----
#pragma unroll
    for (int mt = 0; mt < 4; ++mt) {
        v8h a0  = *reinterpret_cast<const v8h*>(&mbuf[wid][mt * 16 + arow][kgrp * 8]);
        v8h a1v = *reinterpret_cast<const v8h*>(&mbuf[wid][mt * 16 + arow][32 + kgrp * 8]);
        v4f c = {0.f, 0.f, 0.f, 0.f};
        c = __builtin_amdgcn_mfma_f32_16x16x32_f16(a0,  bf3a, c, 0, 0, 0);
        c = __builtin_amdgcn_mfma_f32_16x16x32_f16(a1v, bf3b, c, 0, 0, 0);
        if (arow < 3) {
            float4 st;
            st.x = tanhf(c[0] + bias3);
            st.y = tanhf(c[1] + bias3);
            st.z = tanhf(c[2] + bias3);
            st.w = tanhf(c[3] + bias3);
            size_t idx = ((size_t)b * 3 + arow) * N_PIX
                       + (size_t)(i0 + mt) * IMG + j0 + kgrp * 4;
            *reinterpret_cast<float4*>(&out[idx]) = st;
        }
    }
}

extern "C" void kernel_launch(void* const* d_in, const int* in_sizes, int n_in,
                              void* d_out, int out_size, void* d_ws, size_t ws_size,
                              hipStream_t stream)
{
    const float* z  = (const float*)d_in[0];
    const float* wt = (const float*)d_in[1];
    const float* bt = (const float*)d_in[2];
    const float* w1 = (const float*)d_in[3];
    const float* b1 = (const float*)d_in[4];
    const float* w2 = (const float*)d_in[5];
    const float* b2 = (const float*)d_in[6];
    const float* w3 = (const float*)d_in[7];
    const float* b3 = (const float*)d_in[8];
    float* out  = (float*)d_out;

    char* ws = (char*)d_ws;
    float*     tabs = (float*)ws;                          // 4 MB
    _Float16*  w1T  = (_Float16*)(ws + (4 << 20));         // 4 KB
    _Float16*  w2T  = (_Float16*)(ws + (4 << 20) + 4096);  // 8 KB
    _Float16*  w3T  = (_Float16*)(ws + (4 << 20) + 12288); // 2 KB

    ResArr ra;
    const double growth = std::exp((std::log(256.0) - std::log(16.0)) / 15.0);
    for (int l = 0; l < TABLE_NUM; ++l)
        ra.r[l] = (float)(16.0 * std::pow(growth, (double)l));

    prep_weights<<<1, 256, 0, stream>>>(w1, w2, w3, w1T, w2T, w3T);
    // 3x idempotent launches: gen_dur = (T_R5 - T_R4) / 2
    gen_tables<<<D_TAB / 256, 256, 0, stream>>>(z, wt, bt, tabs);
    gen_tables<<<D_TAB / 256, 256, 0, stream>>>(z, wt, bt, tabs);
    gen_tables<<<D_TAB / 256, 256, 0, stream>>>(z, wt, bt, tabs);
    hash_mlp<<<BATCH * (N_PIX / 256), 256, 0, stream>>>(
        tabs, w1T, w2T, w3T, b1, b2, b3, out, ra);
}

// Round 6
// 121.008 us; speedup vs baseline: 1.9693x; 1.9693x over previous
//
#include <hip/hip_runtime.h>
#include <cmath>

#define TABLE_NUM 16
#define T_SIZE    4096
#define Z_DIM     512
#define IMG       256
#define D_TAB     (TABLE_NUM * T_SIZE * 2)       // 131072
#define BATCH     8
#define HID       64
#define N_PIX     (IMG * IMG)                    // 65536
#define PRIME_Y   2654435761u
#define CPITCH    19                             // corner grid pitch (W,H <= 18)
#define CBUF      (CPITCH * CPITCH)              // 361 float2 entries

typedef _Float16 v8h  __attribute__((ext_vector_type(8)));
typedef _Float16 v2h  __attribute__((ext_vector_type(2)));
typedef float    v4f  __attribute__((ext_vector_type(4)));

struct ResArr { float r[TABLE_NUM]; };

// ---------------------------------------------------------------------------
// Kernel 0: transpose + f16-cast MLP weights to [n][k] (MFMA B layout).
// ---------------------------------------------------------------------------
__global__ void prep_weights(const float* __restrict__ w1, const float* __restrict__ w2,
                             const float* __restrict__ w3,
                             _Float16* __restrict__ w1T, _Float16* __restrict__ w2T,
                             _Float16* __restrict__ w3T)
{
    const int t = threadIdx.x;
    for (int i = t; i < HID * 32; i += 256) {          // w1T[64][32] <- w1[32][64]
        int n = i >> 5, k = i & 31;
        w1T[i] = (_Float16)w1[k * HID + n];
    }
    for (int i = t; i < HID * HID; i += 256) {         // w2T[64][64] <- w2[64][64]
        int n = i >> 6, k = i & 63;
        w2T[i] = (_Float16)w2[k * HID + n];
    }
    for (int i = t; i < 16 * HID; i += 256) {          // w3T[16][64] <- w3[64][3], pad
        int n = i >> 6, k = i & 63;
        w3T[i] = (_Float16)(n < 3 ? w3[k * 3 + n] : 0.f);
    }
}

// ---------------------------------------------------------------------------
// Kernel 1: tables[b][n] = sum_k z[b][k]*w[k][n] + bt[n].  268 MB stream.
// float4: 4 cols/thread (16 B/lane), 256 blocks x 128 thr = 2 waves/CU on all
// 256 CUs. unroll 16 -> 16 KB in flight/wave, 32 KB/CU (>> 9.2 KB BW*lat).
// z reads wave-uniform -> s_load_dwordx16 batches.
// ---------------------------------------------------------------------------
__global__ __launch_bounds__(128) void gen_tables(
    const float* __restrict__ z, const float* __restrict__ w,
    const float* __restrict__ bt, float* __restrict__ tabs)
{
    const int c4 = blockIdx.x * 128 + threadIdx.x;     // float4 column group
    const float4* wp = reinterpret_cast<const float4*>(w) + c4;

    float4 acc[BATCH];
#pragma unroll
    for (int b = 0; b < BATCH; ++b) acc[b] = make_float4(0.f, 0.f, 0.f, 0.f);

#pragma unroll 16
    for (int k = 0; k < Z_DIM; ++k) {
        float4 wv = wp[(size_t)k * (D_TAB / 4)];
#pragma unroll
        for (int b = 0; b < BATCH; ++b) {
            float zv = z[b * Z_DIM + k];               // uniform -> s_load
            acc[b].x = fmaf(zv, wv.x, acc[b].x);
            acc[b].y = fmaf(zv, wv.y, acc[b].y);
            acc[b].z = fmaf(zv, wv.z, acc[b].z);
            acc[b].w = fmaf(zv, wv.w, acc[b].w);
        }
    }

    float4 bv = reinterpret_cast<const float4*>(bt)[c4];
#pragma unroll
    for (int b = 0; b < BATCH; ++b) {
        float4 o;
        o.x = acc[b].x + bv.x;
        o.y = acc[b].y + bv.y;
        o.z = acc[b].z + bv.z;
        o.w = acc[b].w + bv.w;
        reinterpret_cast<float4*>(tabs)[(size_t)b * (D_TAB / 4) + c4] = o;
    }
}

// ---------------------------------------------------------------------------
// Kernel 2: hash-grid + f16-MFMA MLP with cooperative corner staging.
// Gather-lane model (R5 measurement): divergent gathers cost ~1 lane/cyc/CU,
// so the fix is fewer gather LANES. A 16x16-pixel block needs only the
// (<=18x18) corner grid per level: stage it cooperatively (~1250 global
// gather-lanes/block vs 16384 = 13x fewer), serve the 4 bilinear corners
// per pixel from LDS. Double-buffered stage; 1 barrier/level. Level loop
// fully unrolled so res.r[l] is static (no scratch).
// xs/ys from the SAME f32 exprs as pixel coords + monotone f32 mult/floor
// => staged window always covers every pixel's corners.
// ---------------------------------------------------------------------------
__global__ __launch_bounds__(256) void hash_mlp(
    const float* __restrict__ tabs,
    const _Float16* __restrict__ w1T, const _Float16* __restrict__ w2T,
    const _Float16* __restrict__ w3T,
    const float* __restrict__ b1, const float* __restrict__ b2,
    const float* __restrict__ b3,
    float* __restrict__ out, ResArr res)
{
    __shared__ _Float16 mbuf[4][64][72];       // 36.9 KB per-wave MFMA staging
    __shared__ float2   cstage[2][CBUF];       // 5.8 KB corner double-buffer

    const int tid  = threadIdx.x;
    const int wid  = tid >> 6;
    const int lane = tid & 63;
    const int b    = blockIdx.x & 7;          // batch == XCD (round-robin)
    const int tile = blockIdx.x >> 3;         // 16x16 pixel block
    const int i0b  = (tile >> 4) * 16;
    const int j0b  = (tile & 15) * 16;
    const int i0   = i0b + wid * 4;           // this wave's 4 i-rows

    const int di = lane >> 4, dj = lane & 15;
    const float cxp = ((float)(i0 + di) + 0.5f) * (1.0f / IMG);
    const float cyp = ((float)(j0b + dj) + 0.5f) * (1.0f / IMG);
    const float2* tb2 = reinterpret_cast<const float2*>(tabs + (size_t)b * D_TAB);

    // block corner-window bounds (same float exprs as pixel coords)
    const float cx_lo = ((float)i0b + 0.5f)  * (1.0f / IMG);
    const float cx_hi = ((float)i0b + 15.5f) * (1.0f / IMG);
    const float cy_lo = ((float)j0b + 0.5f)  * (1.0f / IMG);
    const float cy_hi = ((float)j0b + 15.5f) * (1.0f / IMG);

    const int tx = tid & 15, ty = tid >> 4;   // 16x16 staging layout

#define STAGE(L, CB)                                                          \
    {                                                                         \
        const float r = res.r[L];                                             \
        const int xs = (int)floorf(cx_lo * r);                                \
        const int xe = (int)floorf(cx_hi * r) + 1;                            \
        const int ys = (int)floorf(cy_lo * r);                                \
        const int ye = (int)floorf(cy_hi * r) + 1;                            \
        const int W = xe - xs + 1, H = ye - ys + 1;                           \
        const float2* tl = tb2 + (L) * T_SIZE;                                \
        for (int yy = ty; yy < H; yy += 16)                                   \
            for (int xx = tx; xx < W; xx += 16) {                             \
                unsigned idx = ((unsigned)(xs + xx) ^                         \
                                ((unsigned)(ys + yy) * PRIME_Y)) & (T_SIZE-1);\
                (CB)[yy * CPITCH + xx] = tl[idx];                             \
            }                                                                 \
    }

#define CONSUME(L, CB)                                                        \
    {                                                                         \
        const float r = res.r[L];                                             \
        const int xs = (int)floorf(cx_lo * r);                                \
        const int ys = (int)floorf(cy_lo * r);                                \
        float px = cxp * r, py = cyp * r;                                     \
        float fx0 = floorf(px), fy0 = floorf(py);                             \
        float fx = px - fx0, fy = py - fy0;                                   \
        int xi = (int)fx0 - xs, yi = (int)fy0 - ys;                           \
        float2 f00 = (CB)[yi * CPITCH + xi];                                  \
        float2 f10 = (CB)[yi * CPITCH + xi + 1];                              \
        float2 f01 = (CB)[(yi + 1) * CPITCH + xi];                            \
        float2 f11 = (CB)[(yi + 1) * CPITCH + xi + 1];                        \
        float w00 = (1.f - fx) * (1.f - fy);                                  \
        float w10 = fx * (1.f - fy);                                          \
        float w01 = (1.f - fx) * fy;                                          \
        float w11 = fx * fy;                                                  \
        float e0 = f00.x * w00 + f10.x * w10 + f01.x * w01 + f11.x * w11;     \
        float e1 = f00.y * w00 + f10.y * w10 + f01.y * w01 + f11.y * w11;     \
        v2h p; p.x = (_Float16)e0; p.y = (_Float16)e1;                        \
        *reinterpret_cast<v2h*>(&mbuf[wid][lane][2 * (L)]) = p;               \
    }

    STAGE(0, cstage[0]);
    __syncthreads();
#pragma unroll
    for (int l = 0; l < TABLE_NUM; ++l) {
        if (l + 1 < TABLE_NUM) STAGE(l + 1, cstage[(l + 1) & 1]);
        CONSUME(l, cstage[l & 1]);
        __syncthreads();
    }
#undef STAGE
#undef CONSUME

    const int arow = lane & 15;        // A row / B col / C col
    const int kgrp = lane >> 4;        // k-group

    float bias1v[4], bias2v[4];
#pragma unroll
    for (int nt = 0; nt < 4; ++nt) {
        bias1v[nt] = b1[nt * 16 + arow];
        bias2v[nt] = b2[nt * 16 + arow];
    }
    const float bias3 = (arow < 3) ? b3[arow] : 0.f;

    v8h bf1[4], bf2a[4], bf2b[4];
#pragma unroll
    for (int nt = 0; nt < 4; ++nt) {
        bf1[nt]  = *reinterpret_cast<const v8h*>(&w1T[(nt * 16 + arow) * 32 + kgrp * 8]);
        bf2a[nt] = *reinterpret_cast<const v8h*>(&w2T[(nt * 16 + arow) * 64 + kgrp * 8]);
        bf2b[nt] = *reinterpret_cast<const v8h*>(&w2T[(nt * 16 + arow) * 64 + 32 + kgrp * 8]);
    }
    v8h bf3a = *reinterpret_cast<const v8h*>(&w3T[arow * 64 + kgrp * 8]);
    v8h bf3b = *reinterpret_cast<const v8h*>(&w3T[arow * 64 + 32 + kgrp * 8]);

    // ---- layer 1: 32 -> 64 ----
    v8h a1[4];
#pragma unroll
    for (int mt = 0; mt < 4; ++mt)
        a1[mt] = *reinterpret_cast<const v8h*>(&mbuf[wid][mt * 16 + arow][kgrp * 8]);

    v4f c1[4][4];
#pragma unroll
    for (int nt = 0; nt < 4; ++nt)
#pragma unroll
        for (int mt = 0; mt < 4; ++mt) {
            v4f c = {0.f, 0.f, 0.f, 0.f};
            c = __builtin_amdgcn_mfma_f32_16x16x32_f16(a1[mt], bf1[nt], c, 0, 0, 0);
#pragma unroll
            for (int e = 0; e < 4; ++e)
                c1[mt][nt][e] = fmaxf(c[e] + bias1v[nt], 0.f);
        }

#pragma unroll
    for (int mt = 0; mt < 4; ++mt)
#pragma unroll
        for (int nt = 0; nt < 4; ++nt)
#pragma unroll
            for (int e = 0; e < 4; ++e)
                mbuf[wid][mt * 16 + kgrp * 4 + e][nt * 16 + arow] = (_Float16)c1[mt][nt][e];

    // ---- layer 2: 64 -> 64 ----
    v8h a2[4][2];
#pragma unroll
    for (int mt = 0; mt < 4; ++mt) {
        a2[mt][0] = *reinterpret_cast<const v8h*>(&mbuf[wid][mt * 16 + arow][kgrp * 8]);
        a2[mt][1] = *reinterpret_cast<const v8h*>(&mbuf[wid][mt * 16 + arow][32 + kgrp * 8]);
    }
    v4f c2[4][4];
#pragma unroll
    for (int nt = 0; nt < 4; ++nt)
#pragma unroll
        for (int mt = 0; mt < 4; ++mt) {
            v4f c = {0.f, 0.f, 0.f, 0.f};
            c = __builtin_amdgcn_mfma_f32_16x16x32_f16(a2[mt][0], bf2a[nt], c, 0, 0, 0);
            c = __builtin_amdgcn_mfma_f32_16x16x32_f16(a2[mt][1], bf2b[nt], c, 0, 0, 0);
#pragma unroll
            for (int e = 0; e < 4; ++e)
                c2[mt][nt][e] = fmaxf(c[e] + bias2v[nt], 0.f);
        }

#pragma unroll
    for (int mt = 0; mt < 4; ++mt)
#pragma unroll
        for (int nt = 0; nt < 4; ++nt)
#pragma unroll
            for (int e = 0; e < 4; ++e)
                mbuf[wid][mt * 16 + kgrp * 4 + e][nt * 16 + arow] = (_Float16)c2[mt][nt][e];

    // ---- layer 3: 64 -> 3 (padded 16), tanh, coalesced row stores ----
#pragma unroll
    for (int mt = 0; mt < 4; ++mt) {
        v8h a0  = *reinterpret_cast<const v8h*>(&mbuf[wid][mt * 16 + arow][kgrp * 8]);
        v8h a1v = *reinterpret_cast<const v8h*>(&mbuf[wid][mt * 16 + arow][32 + kgrp * 8]);
        v4f c = {0.f, 0.f, 0.f, 0.f};
        c = __builtin_amdgcn_mfma_f32_16x16x32_f16(a0,  bf3a, c, 0, 0, 0);
        c = __builtin_amdgcn_mfma_f32_16x16x32_f16(a1v, bf3b, c, 0, 0, 0);
        if (arow < 3) {
            float4 st;
            st.x = tanhf(c[0] + bias3);
            st.y = tanhf(c[1] + bias3);
            st.z = tanhf(c[2] + bias3);
            st.w = tanhf(c[3] + bias3);
            // pixel m = mt*16 + kgrp*4 + e -> i = i0+mt, j = j0b+kgrp*4+e
            size_t idx = ((size_t)b * 3 + arow) * N_PIX
                       + (size_t)(i0 + mt) * IMG + j0b + kgrp * 4;
            *reinterpret_cast<float4*>(&out[idx]) = st;
        }
    }
}

extern "C" void kernel_launch(void* const* d_in, const int* in_sizes, int n_in,
                              void* d_out, int out_size, void* d_ws, size_t ws_size,
                              hipStream_t stream)
{
    const float* z  = (const float*)d_in[0];
    const float* wt = (const float*)d_in[1];
    const float* bt = (const float*)d_in[2];
    const float* w1 = (const float*)d_in[3];
    const float* b1 = (const float*)d_in[4];
    const float* w2 = (const float*)d_in[5];
    const float* b2 = (const float*)d_in[6];
    const float* w3 = (const float*)d_in[7];
    const float* b3 = (const float*)d_in[8];
    float* out  = (float*)d_out;

    char* ws = (char*)d_ws;
    float*     tabs = (float*)ws;                          // 4 MB
    _Float16*  w1T  = (_Float16*)(ws + (4 << 20));         // 4 KB
    _Float16*  w2T  = (_Float16*)(ws + (4 << 20) + 4096);  // 8 KB
    _Float16*  w3T  = (_Float16*)(ws + (4 << 20) + 12288); // 2 KB

    ResArr ra;
    const double growth = std::exp((std::log(256.0) - std::log(16.0)) / 15.0);
    for (int l = 0; l < TABLE_NUM; ++l)
        ra.r[l] = (float)(16.0 * std::pow(growth, (double)l));

    prep_weights<<<1, 256, 0, stream>>>(w1, w2, w3, w1T, w2T, w3T);
    gen_tables<<<D_TAB / 4 / 128, 128, 0, stream>>>(z, wt, bt, tabs);
    hash_mlp<<<BATCH * (N_PIX / 256), 256, 0, stream>>>(
        tabs, w1T, w2T, w3T, b1, b2, b3, out, ra);
}

// Round 7
// 99.368 us; speedup vs baseline: 2.3982x; 1.2178x over previous
//
#include <hip/hip_runtime.h>
#include <cmath>

#define TABLE_NUM 16
#define T_SIZE    4096
#define Z_DIM     512
#define IMG       256
#define D_TAB     (TABLE_NUM * T_SIZE * 2)       // 131072
#define BATCH     8
#define HID       64
#define N_PIX     (IMG * IMG)                    // 65536
#define PRIME_Y   2654435761u
#define KCHUNK    4                              // k-split chunks
#define KLEN      (Z_DIM / KCHUNK)               // 128
#define NG4       (D_TAB / 4)                    // 32768 float4 col-groups

typedef _Float16 v8h  __attribute__((ext_vector_type(8)));
typedef _Float16 v2h  __attribute__((ext_vector_type(2)));
typedef float    v4f  __attribute__((ext_vector_type(4)));

struct ResArr { float r[TABLE_NUM]; };

// ---------------------------------------------------------------------------
// Kernel 0: weight transpose/cast + z transpose (zT[k][b] so the gen kernel
// reads all 8 batch scalars with one uniform s_load_dwordx8 per k).
// ---------------------------------------------------------------------------
__global__ void prep_weights(const float* __restrict__ w1, const float* __restrict__ w2,
                             const float* __restrict__ w3, const float* __restrict__ z,
                             _Float16* __restrict__ w1T, _Float16* __restrict__ w2T,
                             _Float16* __restrict__ w3T, float* __restrict__ zT)
{
    const int t = threadIdx.x;
    for (int i = t; i < HID * 32; i += 256) {          // w1T[64][32] <- w1[32][64]
        int n = i >> 5, k = i & 31;
        w1T[i] = (_Float16)w1[k * HID + n];
    }
    for (int i = t; i < HID * HID; i += 256) {         // w2T[64][64] <- w2[64][64]
        int n = i >> 6, k = i & 63;
        w2T[i] = (_Float16)w2[k * HID + n];
    }
    for (int i = t; i < 16 * HID; i += 256) {          // w3T[16][64] <- w3[64][3], pad
        int n = i >> 6, k = i & 63;
        w3T[i] = (_Float16)(n < 3 ? w3[k * 3 + n] : 0.f);
    }
    for (int i = t; i < Z_DIM * BATCH; i += 256) {     // zT[k][b] <- z[b][k]
        int k = i >> 3, b = i & 7;
        zT[i] = z[b * Z_DIM + k];
    }
}

// ---------------------------------------------------------------------------
// Kernel 1a: partial GEMM over one k-chunk.  float4 width AND 8 waves/CU:
// 4 chunks x 32768 col-group threads = 512 blocks x 256 thr (2 blocks/CU).
// Per k: 1 s_load_dwordx8 (zT row) + 1 global float4 + 32 FMA.
// unroll 8 -> 8 KB in flight/wave, 64 KB/CU (>> 9.2 KB BW*latency).
// part[c][b][g] f32x4 partial sums (16 MB).
// ---------------------------------------------------------------------------
__global__ __launch_bounds__(256) void gen_partial(
    const float* __restrict__ zT, const float* __restrict__ w,
    float* __restrict__ part)
{
    const int c  = blockIdx.x >> 7;                      // chunk 0..3
    const int g  = (blockIdx.x & 127) * 256 + threadIdx.x;  // col-group
    const int k0 = c * KLEN;
    const float4* wp = reinterpret_cast<const float4*>(w) + g;

    float4 acc[BATCH];
#pragma unroll
    for (int b = 0; b < BATCH; ++b) acc[b] = make_float4(0.f, 0.f, 0.f, 0.f);

#pragma unroll 8
    for (int kk = 0; kk < KLEN; ++kk) {
        const int k = k0 + kk;
        float4 wv = wp[(size_t)k * NG4];
        const float* zr = zT + k * BATCH;                // uniform -> s_load x8
#pragma unroll
        for (int b = 0; b < BATCH; ++b) {
            float zv = zr[b];
            acc[b].x = fmaf(zv, wv.x, acc[b].x);
            acc[b].y = fmaf(zv, wv.y, acc[b].y);
            acc[b].z = fmaf(zv, wv.z, acc[b].z);
            acc[b].w = fmaf(zv, wv.w, acc[b].w);
        }
    }

    float4* pp = reinterpret_cast<float4*>(part);
#pragma unroll
    for (int b = 0; b < BATCH; ++b)
        pp[((size_t)(c * BATCH + b) << 15) + g] = acc[b];
}

// ---------------------------------------------------------------------------
// Kernel 1b: tabs[b][g] = sum_c part[c][b][g] + bt[g].  ~20 MB traffic.
// ---------------------------------------------------------------------------
__global__ __launch_bounds__(256) void gen_reduce(
    const float* __restrict__ part, const float* __restrict__ bt,
    float* __restrict__ tabs)
{
    const int i = blockIdx.x * 256 + threadIdx.x;        // 0 .. 8*32768-1
    const int b = i >> 15, g = i & (NG4 - 1);
    const float4* pp = reinterpret_cast<const float4*>(part);

    float4 s = pp[((size_t)(0 * BATCH + b) << 15) + g];
#pragma unroll
    for (int c = 1; c < KCHUNK; ++c) {
        float4 p = pp[((size_t)(c * BATCH + b) << 15) + g];
        s.x += p.x; s.y += p.y; s.z += p.z; s.w += p.w;
    }
    float4 bv = reinterpret_cast<const float4*>(bt)[g];
    s.x += bv.x; s.y += bv.y; s.z += bv.z; s.w += bv.w;
    reinterpret_cast<float4*>(tabs)[((size_t)b << 15) + g] = s;
}

// ---------------------------------------------------------------------------
// Kernel 2: fused hash-grid + f16-MFMA MLP — R4 version verbatim (measured
// ~48 us via the R5 split). 4x16 pixel tile per wave; mbuf per-wave (no
// barriers); batch == XCD round-robin for table L2 affinity.
// ---------------------------------------------------------------------------
__global__ __launch_bounds__(256) void hash_mlp(
    const float* __restrict__ tabs,
    const _Float16* __restrict__ w1T, const _Float16* __restrict__ w2T,
    const _Float16* __restrict__ w3T,
    const float* __restrict__ b1, const float* __restrict__ b2,
    const float* __restrict__ b3,
    float* __restrict__ out, ResArr res)
{
    __shared__ _Float16 mbuf[4][64][72];
    const int tid  = threadIdx.x;
    const int wid  = tid >> 6;
    const int lane = tid & 63;
    const int b    = blockIdx.x & 7;          // batch == XCD (round-robin)
    const int tile = blockIdx.x >> 3;         // 0..255 -> 16x16 block of pixels
    const int ti   = tile >> 4;
    const int tj   = tile & 15;
    const int i0   = ti * 16 + wid * 4;       // this wave's 4 i-rows
    const int j0   = tj * 16;                 // 16 j-cols

    const int di = lane >> 4, dj = lane & 15;
    const float cx = ((float)(i0 + di) + 0.5f) * (1.0f / IMG);
    const float cy = ((float)(j0 + dj) + 0.5f) * (1.0f / IMG);
    const float* tb = tabs + (size_t)b * D_TAB;
    const float2* tb2 = reinterpret_cast<const float2*>(tb);

    // ---- hash-grid features: 16 levels, f16 pairs straight to LDS ----
#pragma unroll 4
    for (int l = 0; l < TABLE_NUM; ++l) {
        float r  = res.r[l];
        float px = cx * r, py = cy * r;
        float fx0 = floorf(px), fy0 = floorf(py);
        float fx = px - fx0, fy = py - fy0;
        unsigned x0 = (unsigned)(int)fx0, y0 = (unsigned)(int)fy0;
        unsigned hy0 = y0 * PRIME_Y, hy1 = (y0 + 1u) * PRIME_Y;
        unsigned i00 = (x0 ^ hy0) & (T_SIZE - 1);
        unsigned i10 = ((x0 + 1u) ^ hy0) & (T_SIZE - 1);
        unsigned i01 = (x0 ^ hy1) & (T_SIZE - 1);
        unsigned i11 = ((x0 + 1u) ^ hy1) & (T_SIZE - 1);
        const float2* tl = tb2 + l * T_SIZE;
        float2 f00 = tl[i00], f10 = tl[i10], f01 = tl[i01], f11 = tl[i11];
        float w00 = (1.f - fx) * (1.f - fy);
        float w10 = fx * (1.f - fy);
        float w01 = (1.f - fx) * fy;
        float w11 = fx * fy;
        float e0 = f00.x * w00 + f10.x * w10 + f01.x * w01 + f11.x * w11;
        float e1 = f00.y * w00 + f10.y * w10 + f01.y * w01 + f11.y * w11;
        v2h p; p.x = (_Float16)e0; p.y = (_Float16)e1;
        *reinterpret_cast<v2h*>(&mbuf[wid][lane][2 * l]) = p;
    }

    const int arow = lane & 15;        // A row / B col / C col
    const int kgrp = lane >> 4;        // k-group

    float bias1v[4], bias2v[4];
#pragma unroll
    for (int nt = 0; nt < 4; ++nt) {
        bias1v[nt] = b1[nt * 16 + arow];
        bias2v[nt] = b2[nt * 16 + arow];
    }
    const float bias3 = (arow < 3) ? b3[arow] : 0.f;

    v8h bf1[4], bf2a[4], bf2b[4];
#pragma unroll
    for (int nt = 0; nt < 4; ++nt) {
        bf1[nt]  = *reinterpret_cast<const v8h*>(&w1T[(nt * 16 + arow) * 32 + kgrp * 8]);
        bf2a[nt] = *reinterpret_cast<const v8h*>(&w2T[(nt * 16 + arow) * 64 + kgrp * 8]);
        bf2b[nt] = *reinterpret_cast<const v8h*>(&w2T[(nt * 16 + arow) * 64 + 32 + kgrp * 8]);
    }
    v8h bf3a = *reinterpret_cast<const v8h*>(&w3T[arow * 64 + kgrp * 8]);
    v8h bf3b = *reinterpret_cast<const v8h*>(&w3T[arow * 64 + 32 + kgrp * 8]);

    // ---- layer 1: 32 -> 64 ----
    v8h a1[4];
#pragma unroll
    for (int mt = 0; mt < 4; ++mt)
        a1[mt] = *reinterpret_cast<const v8h*>(&mbuf[wid][mt * 16 + arow][kgrp * 8]);

    v4f c1[4][4];
#pragma unroll
    for (int nt = 0; nt < 4; ++nt)
#pragma unroll
        for (int mt = 0; mt < 4; ++mt) {
            v4f c = {0.f, 0.f, 0.f, 0.f};
            c = __builtin_amdgcn_mfma_f32_16x16x32_f16(a1[mt], bf1[nt], c, 0, 0, 0);
#pragma unroll
            for (int e = 0; e < 4; ++e)
                c1[mt][nt][e] = fmaxf(c[e] + bias1v[nt], 0.f);
        }

#pragma unroll
    for (int mt = 0; mt < 4; ++mt)
#pragma unroll
        for (int nt = 0; nt < 4; ++nt)
#pragma unroll
            for (int e = 0; e < 4; ++e)
                mbuf[wid][mt * 16 + kgrp * 4 + e][nt * 16 + arow] = (_Float16)c1[mt][nt][e];

    // ---- layer 2: 64 -> 64 ----
    v8h a2[4][2];
#pragma unroll
    for (int mt = 0; mt < 4; ++mt) {
        a2[mt][0] = *reinterpret_cast<const v8h*>(&mbuf[wid][mt * 16 + arow][kgrp * 8]);
        a2[mt][1] = *reinterpret_cast<const v8h*>(&mbuf[wid][mt * 16 + arow][32 + kgrp * 8]);
    }
    v4f c2[4][4];
#pragma unroll
    for (int nt = 0; nt < 4; ++nt)
#pragma unroll
        for (int mt = 0; mt < 4; ++mt) {
            v4f c = {0.f, 0.f, 0.f, 0.f};
            c = __builtin_amdgcn_mfma_f32_16x16x32_f16(a2[mt][0], bf2a[nt], c, 0, 0, 0);
            c = __builtin_amdgcn_mfma_f32_16x16x32_f16(a2[mt][1], bf2b[nt], c, 0, 0, 0);
#pragma unroll
            for (int e = 0; e < 4; ++e)
                c2[mt][nt][e] = fmaxf(c[e] + bias2v[nt], 0.f);
        }

#pragma unroll
    for (int mt = 0; mt < 4; ++mt)
#pragma unroll
        for (int nt = 0; nt < 4; ++nt)
#pragma unroll
            for (int e = 0; e < 4; ++e)
                mbuf[wid][mt * 16 + kgrp * 4 + e][nt * 16 + arow] = (_Float16)c2[mt][nt][e];

    // ---- layer 3: 64 -> 3 (padded 16), tanh, coalesced row stores ----
#pragma unroll
    for (int mt = 0; mt < 4; ++mt) {
        v8h a0  = *reinterpret_cast<const v8h*>(&mbuf[wid][mt * 16 + arow][kgrp * 8]);
        v8h a1v = *reinterpret_cast<const v8h*>(&mbuf[wid][mt * 16 + arow][32 + kgrp * 8]);
        v4f c = {0.f, 0.f, 0.f, 0.f};
        c = __builtin_amdgcn_mfma_f32_16x16x32_f16(a0,  bf3a, c, 0, 0, 0);
        c = __builtin_amdgcn_mfma_f32_16x16x32_f16(a1v, bf3b, c, 0, 0, 0);
        if (arow < 3) {
            float4 st;
            st.x = tanhf(c[0] + bias3);
            st.y = tanhf(c[1] + bias3);
            st.z = tanhf(c[2] + bias3);
            st.w = tanhf(c[3] + bias3);
            size_t idx = ((size_t)b * 3 + arow) * N_PIX
                       + (size_t)(i0 + mt) * IMG + j0 + kgrp * 4;
            *reinterpret_cast<float4*>(&out[idx]) = st;
        }
    }
}

extern "C" void kernel_launch(void* const* d_in, const int* in_sizes, int n_in,
                              void* d_out, int out_size, void* d_ws, size_t ws_size,
                              hipStream_t stream)
{
    const float* z  = (const float*)d_in[0];
    const float* wt = (const float*)d_in[1];
    const float* bt = (const float*)d_in[2];
    const float* w1 = (const float*)d_in[3];
    const float* b1 = (const float*)d_in[4];
    const float* w2 = (const float*)d_in[5];
    const float* b2 = (const float*)d_in[6];
    const float* w3 = (const float*)d_in[7];
    const float* b3 = (const float*)d_in[8];
    float* out  = (float*)d_out;

    char* ws = (char*)d_ws;
    float*     tabs = (float*)ws;                            // 4 MB
    float*     part = (float*)(ws + (4 << 20));              // 16 MB partials
    _Float16*  w1T  = (_Float16*)(ws + (20 << 20));          // 4 KB
    _Float16*  w2T  = (_Float16*)(ws + (20 << 20) + 4096);   // 8 KB
    _Float16*  w3T  = (_Float16*)(ws + (20 << 20) + 12288);  // 2 KB
    float*     zT   = (float*)(ws + (20 << 20) + 16384);     // 16 KB

    ResArr ra;
    const double growth = std::exp((std::log(256.0) - std::log(16.0)) / 15.0);
    for (int l = 0; l < TABLE_NUM; ++l)
        ra.r[l] = (float)(16.0 * std::pow(growth, (double)l));

    prep_weights<<<1, 256, 0, stream>>>(w1, w2, w3, z, w1T, w2T, w3T, zT);
    gen_partial<<<KCHUNK * (NG4 / 256), 256, 0, stream>>>(zT, wt, part);
    gen_reduce<<<BATCH * NG4 / 256, 256, 0, stream>>>(part, bt, tabs);
    hash_mlp<<<BATCH * (N_PIX / 256), 256, 0, stream>>>(
        tabs, w1T, w2T, w3T, b1, b2, b3, out, ra);
}